// Round 3
// baseline (675.465 us; speedup 1.0000x reference)
//
#include <hip/hip_runtime.h>
#include <hip/hip_bf16.h>
#include <stdint.h>

#define B_ROWS 16384
#define DIM 2048
#define BM 128
#define BN 128
#define BK 64

typedef float f32x4 __attribute__((ext_vector_type(4)));
typedef short bf16x8 __attribute__((ext_vector_type(8)));
using u16 = unsigned short;
using u32 = unsigned int;

__device__ __forceinline__ u32 pack_bf2(float a, float b) {
  __hip_bfloat162 t = __float22bfloat162_rn(float2{a, b});
  union { __hip_bfloat162 b2; u32 u; } cv;
  cv.b2 = t;
  return cv.u;
}

__device__ __forceinline__ u16 f2bf_rne(float f) {
  union { float f; u32 u; } v;
  v.f = f;
  u32 u = v.u;
  u32 r = u + 0x7FFFu + ((u >> 16) & 1u);
  return (u16)(r >> 16);
}

__device__ __forceinline__ void gload16(const void* g, void* l) {
  __builtin_amdgcn_global_load_lds(
      (const __attribute__((address_space(1))) u32*)g,
      (__attribute__((address_space(3))) u32*)l, 16, 0, 0);
}

// ---- prepass: flags (fp64 last-col dot) + x->bf16 + compacted h rows -------
__global__ __launch_bounds__(256) void k_prep(
    const float* __restrict__ x, const float* __restrict__ h,
    const float* __restrict__ W_ih, int* __restrict__ flags,
    u16* __restrict__ xb, u16* __restrict__ hCF, u16* __restrict__ hCI,
    int* __restrict__ rowmapF, int* __restrict__ rowmapI,
    int* __restrict__ counts) {
  int row = blockIdx.x * 4 + (threadIdx.x >> 6);
  int lane = threadIdx.x & 63;
  const float* xr = x + (size_t)row * DIM;
  const float* hr = h + (size_t)row * DIM;
  const float* wr = W_ih + (size_t)(DIM - 1) * DIM;
  u16* xbr = xb + (size_t)row * DIM;
  double s = 0.0;
  u32 hp[16];
#pragma unroll
  for (int i = 0; i < 8; ++i) {
    int idx = (i * 64 + lane) * 4;
    f32x4 xv = *(const f32x4*)(xr + idx);
    f32x4 wv = *(const f32x4*)(wr + idx);
    f32x4 hv = *(const f32x4*)(hr + idx);
    s += (double)xv.x * wv.x + (double)xv.y * wv.y +
         (double)xv.z * wv.z + (double)xv.w * wv.w;
    *(uint2*)(xbr + idx) = uint2{pack_bf2(xv.x, xv.y), pack_bf2(xv.z, xv.w)};
    hp[2 * i] = pack_bf2(hv.x, hv.y);
    hp[2 * i + 1] = pack_bf2(hv.z, hv.w);
  }
#pragma unroll
  for (int off = 32; off > 0; off >>= 1) s += __shfl_xor(s, off);
  int f = 3;
  int pos = 0;
  if (lane == 0) {
    bool not_trig = (s >= -1.0);
    float hl = hr[DIM - 1];
    if (!not_trig) f = 2;
    else if (hl > 0.f) f = 0;
    else if (hl < 0.f) f = 1;
    else f = 3;
    flags[row] = f;
    if (f <= 1) {
      pos = atomicAdd(&counts[f], 1);
      (f == 0 ? rowmapF : rowmapI)[pos] = row;
    }
  }
  f = __shfl(f, 0);
  if (f <= 1) {
    pos = __shfl(pos, 0);
    u16* dst = (f == 0 ? hCF : hCI) + (size_t)pos * DIM;
#pragma unroll
    for (int i = 0; i < 8; ++i) {
      int idx = (i * 64 + lane) * 4;
      *(uint2*)(dst + idx) = uint2{hp[2 * i], hp[2 * i + 1]};
    }
  }
}

// ---- flags only (fallback path) --------------------------------------------
__global__ __launch_bounds__(256) void k_flags_fb(
    const float* __restrict__ x, const float* __restrict__ h,
    const float* __restrict__ W_ih, int* __restrict__ flags) {
  int row = blockIdx.x * 4 + (threadIdx.x >> 6);
  int lane = threadIdx.x & 63;
  const float* xr = x + (size_t)row * DIM;
  const float* wr = W_ih + (size_t)(DIM - 1) * DIM;
  double s = 0.0;
#pragma unroll
  for (int i = 0; i < 8; ++i) {
    int idx = (i * 64 + lane) * 4;
    f32x4 xv = *(const f32x4*)(xr + idx);
    f32x4 wv = *(const f32x4*)(wr + idx);
    s += (double)xv.x * wv.x + (double)xv.y * wv.y +
         (double)xv.z * wv.z + (double)xv.w * wv.w;
  }
#pragma unroll
  for (int off = 32; off > 0; off >>= 1) s += __shfl_xor(s, off);
  if (lane == 0) {
    bool not_trig = (s >= -1.0);
    float hl = h[(size_t)row * DIM + (DIM - 1)];
    int f;
    if (!not_trig) f = 2;
    else if (hl > 0.f) f = 0;
    else if (hl < 0.f) f = 1;
    else f = 3;
    flags[row] = f;
  }
}

// ---- convert W_ih ([N][K] already) f32 -> bf16 ------------------------------
__global__ __launch_bounds__(256) void k_convert(const float* __restrict__ src,
                                                 u16* __restrict__ dst) {
  size_t i = ((size_t)blockIdx.x * 256 + threadIdx.x) * 4;
  f32x4 v = *(const f32x4*)(src + i);
  *(uint2*)(dst + i) = uint2{pack_bf2(v.x, v.y), pack_bf2(v.z, v.w)};
}

// ---- transpose+convert [K][N] f32 -> [N][K] bf16 ----------------------------
__global__ __launch_bounds__(256) void k_transpose(const float* __restrict__ src,
                                                   u16* __restrict__ dst) {
  __shared__ float tile[32][33];
  int k0 = blockIdx.x * 32;
  int n0 = blockIdx.y * 32;
  int tx = threadIdx.x & 31;
  int ty = threadIdx.x >> 5;
#pragma unroll
  for (int i = 0; i < 4; ++i)
    tile[ty + 8 * i][tx] = src[(size_t)(k0 + ty + 8 * i) * DIM + n0 + tx];
  __syncthreads();
#pragma unroll
  for (int i = 0; i < 4; ++i)
    dst[(size_t)(n0 + ty + 8 * i) * DIM + k0 + tx] = f2bf_rne(tile[tx][ty + 8 * i]);
}

// ---- GEMM-1: out = xb @ Wih^T (+ h for pass rows) ---------------------------
__global__ __launch_bounds__(256, 2) void k_gemm1(
    const u16* __restrict__ xb, const u16* __restrict__ Wih,
    const int* __restrict__ flags, const float* __restrict__ h,
    float* __restrict__ out) {
  __shared__ char smem[(BM + BN) * BK * 2];
  char* sA = smem;
  char* sB = smem + BM * BK * 2;

  int o = blockIdx.x;
  int swz = (o & 7) * ((int)gridDim.x >> 3) + (o >> 3);
  int brow = (swz >> 4) * BM;
  int bcol = (swz & 15) * BN;

  int t = threadIdx.x;
  int lane = t & 63;
  int wave = t >> 6;
  int wrow = (wave >> 1) * 64;
  int wcol = (wave & 1) * 64;

  f32x4 acc[4][4] = {};

  int aOff[4][2], bOff[4][2];
#pragma unroll
  for (int m = 0; m < 4; ++m)
#pragma unroll
    for (int kk = 0; kk < 2; ++kk) {
      int ar = wrow + m * 16 + (lane & 15);
      aOff[m][kk] = ar * (BK * 2) + ((kk * 64 + (lane >> 4) * 16) ^ ((ar & 7) << 4));
      int br = wcol + m * 16 + (lane & 15);
      bOff[m][kk] = br * (BK * 2) + ((kk * 64 + (lane >> 4) * 16) ^ ((br & 7) << 4));
    }

  int srow = lane >> 3;
  int schunk = lane & 7;
  int sxor = (schunk * 16) ^ (srow << 4);
  const char* Abase = (const char*)(xb + (size_t)brow * DIM);
  const char* Bbase = (const char*)(Wih + (size_t)bcol * DIM);

#pragma unroll 1
  for (int k0 = 0; k0 < DIM; k0 += BK) {
    __syncthreads();
#pragma unroll
    for (int i = 0; i < 4; ++i) {
      int rbase = i * 32 + wave * 8;
      size_t roff = (size_t)(rbase + srow) * (DIM * 2) + (size_t)(k0 * 2) + sxor;
      gload16(Abase + roff, sA + rbase * (BK * 2));
      gload16(Bbase + roff, sB + rbase * (BK * 2));
    }
    __syncthreads();
    bf16x8 aF[4][2], bF[4][2];
#pragma unroll
    for (int m = 0; m < 4; ++m)
#pragma unroll
      for (int kk = 0; kk < 2; ++kk) {
        aF[m][kk] = *(const bf16x8*)(sA + aOff[m][kk]);
        bF[m][kk] = *(const bf16x8*)(sB + bOff[m][kk]);
      }
#pragma unroll
    for (int kk = 0; kk < 2; ++kk)
#pragma unroll
      for (int m = 0; m < 4; ++m)
#pragma unroll
        for (int n = 0; n < 4; ++n)
          acc[m][n] = __builtin_amdgcn_mfma_f32_16x16x32_bf16(
              aF[m][kk], bF[n][kk], acc[m][n], 0, 0, 0);
  }

#pragma unroll
  for (int m = 0; m < 4; ++m) {
    int rbase = brow + wrow + m * 16 + (lane >> 4) * 4;
#pragma unroll
    for (int j = 0; j < 4; ++j) {
      int row = rbase + j;
      bool pass = (flags[row] == 2);
#pragma unroll
      for (int n = 0; n < 4; ++n) {
        int col = bcol + wcol + n * 16 + (lane & 15);
        float v = acc[m][n][j];
        if (pass) v += h[(size_t)row * DIM + col];
        out[(size_t)row * DIM + col] = v;
      }
    }
  }
}

// ---- GEMM-2: grouped compacted-h GEMM, scatter-add into out -----------------
__global__ __launch_bounds__(256, 2) void k_gemm2(
    const u16* __restrict__ hCF, const u16* __restrict__ hCI,
    const u16* __restrict__ WhhT, const u16* __restrict__ WinvT,
    const int* __restrict__ rowmapF, const int* __restrict__ rowmapI,
    const int* __restrict__ counts, float* __restrict__ out) {
  __shared__ char smem[(BM + BN) * BK * 2];
  char* sA = smem;
  char* sB = smem + BM * BK * 2;

  int o = blockIdx.x;
  int swz = (o & 7) * ((int)gridDim.x >> 3) + (o >> 3);
  int g = swz >> 11;                    // 0: fwd (WhhT), 1: inv (WinvT)
  int t2 = swz & 2047;
  int brow = (t2 >> 4) * BM;
  int bcol = (t2 & 15) * BN;

  int cnt = counts[g];
  if (brow >= cnt) return;              // whole tile beyond group extent

  const u16* Ab = g ? hCI : hCF;
  const u16* Bb = g ? WinvT : WhhT;
  const int* rmap = g ? rowmapI : rowmapF;

  int t = threadIdx.x;
  int lane = t & 63;
  int wave = t >> 6;
  int wrow = (wave >> 1) * 64;
  int wcol = (wave & 1) * 64;

  f32x4 acc[4][4] = {};

  int aOff[4][2], bOff[4][2];
#pragma unroll
  for (int m = 0; m < 4; ++m)
#pragma unroll
    for (int kk = 0; kk < 2; ++kk) {
      int ar = wrow + m * 16 + (lane & 15);
      aOff[m][kk] = ar * (BK * 2) + ((kk * 64 + (lane >> 4) * 16) ^ ((ar & 7) << 4));
      int br = wcol + m * 16 + (lane & 15);
      bOff[m][kk] = br * (BK * 2) + ((kk * 64 + (lane >> 4) * 16) ^ ((br & 7) << 4));
    }

  int srow = lane >> 3;
  int schunk = lane & 7;
  int sxor = (schunk * 16) ^ (srow << 4);
  const char* Abase = (const char*)(Ab + (size_t)brow * DIM);
  const char* Bbase = (const char*)(Bb + (size_t)bcol * DIM);

#pragma unroll 1
  for (int k0 = 0; k0 < DIM; k0 += BK) {
    __syncthreads();
#pragma unroll
    for (int i = 0; i < 4; ++i) {
      int rbase = i * 32 + wave * 8;
      size_t roff = (size_t)(rbase + srow) * (DIM * 2) + (size_t)(k0 * 2) + sxor;
      gload16(Abase + roff, sA + rbase * (BK * 2));
      gload16(Bbase + roff, sB + rbase * (BK * 2));
    }
    __syncthreads();
    bf16x8 aF[4][2], bF[4][2];
#pragma unroll
    for (int m = 0; m < 4; ++m)
#pragma unroll
      for (int kk = 0; kk < 2; ++kk) {
        aF[m][kk] = *(const bf16x8*)(sA + aOff[m][kk]);
        bF[m][kk] = *(const bf16x8*)(sB + bOff[m][kk]);
      }
#pragma unroll
    for (int kk = 0; kk < 2; ++kk)
#pragma unroll
      for (int m = 0; m < 4; ++m)
#pragma unroll
        for (int n = 0; n < 4; ++n)
          acc[m][n] = __builtin_amdgcn_mfma_f32_16x16x32_bf16(
              aF[m][kk], bF[n][kk], acc[m][n], 0, 0, 0);
  }

  // scatter-add epilogue (rows beyond cnt are garbage -> skipped)
#pragma unroll
  for (int m = 0; m < 4; ++m) {
    int crbase = brow + wrow + m * 16 + (lane >> 4) * 4;
#pragma unroll
    for (int j = 0; j < 4; ++j) {
      int cr = crbase + j;
      if (cr < cnt) {
        int dst = rmap[cr];
#pragma unroll
        for (int n = 0; n < 4; ++n) {
          int col = bcol + wcol + n * 16 + (lane & 15);
          size_t idx = (size_t)dst * DIM + col;
          out[idx] += acc[m][n][j];
        }
      }
    }
  }
}

// ---- fallback (ws too small): R1 reg-staged 3-segment masked GEMM -----------
__global__ __launch_bounds__(256, 2) void k_gemm_fb(
    const float* __restrict__ x, const float* __restrict__ h,
    const u16* __restrict__ Wih, const u16* __restrict__ WhhT,
    const u16* __restrict__ WinvT, const int* __restrict__ flags,
    float* __restrict__ out) {
  __shared__ char smem[(BM + BN) * BK * 2];
  char* sA = smem;
  char* sB = smem + BM * BK * 2;

  int o = blockIdx.x;
  int swz = (o & 7) * ((int)gridDim.x >> 3) + (o >> 3);
  int brow = (swz >> 4) * BM;
  int bcol = (swz & 15) * BN;

  int t = threadIdx.x;
  int lane = t & 63;
  int wave = t >> 6;
  int wrow = (wave >> 1) * 64;
  int wcol = (wave & 1) * 64;

  f32x4 acc[4][4] = {};
  int sc = t & 15;
  int sr0 = t >> 4;

  int aOff[4][2], bOff[4][2];
#pragma unroll
  for (int m = 0; m < 4; ++m)
#pragma unroll
    for (int kk = 0; kk < 2; ++kk) {
      int ar = wrow + m * 16 + (lane & 15);
      aOff[m][kk] = ar * (BK * 2) + ((kk * 64 + (lane >> 4) * 16) ^ ((ar & 7) << 4));
      int br = wcol + m * 16 + (lane & 15);
      bOff[m][kk] = br * (BK * 2) + ((kk * 64 + (lane >> 4) * 16) ^ ((br & 7) << 4));
    }

#pragma unroll 1
  for (int seg = 0; seg < 3; ++seg) {
    const float* Asrc = (seg == 0) ? x : h;
    const u16* Bsrc = (seg == 0) ? Wih : (seg == 1) ? WhhT : WinvT;
    int want = seg - 1;

    float rmask[8];
#pragma unroll
    for (int i = 0; i < 8; ++i) {
      int r = sr0 + 16 * i;
      rmask[i] = (want < 0 || flags[brow + r] == want) ? 1.f : 0.f;
    }

#pragma unroll 1
    for (int k0 = 0; k0 < DIM; k0 += BK) {
      __syncthreads();
#pragma unroll
      for (int i = 0; i < 8; ++i) {
        int r = sr0 + 16 * i;
        f32x4 v = *(const f32x4*)(Asrc + (size_t)(brow + r) * DIM + k0 + sc * 4);
        float msk = rmask[i];
        int off = r * (BK * 2) + ((sc * 8) ^ ((r & 7) << 4));
        *(uint2*)(sA + off) =
            uint2{pack_bf2(v.x * msk, v.y * msk), pack_bf2(v.z * msk, v.w * msk)};
      }
#pragma unroll
      for (int i = 0; i < 4; ++i) {
        int ch = t + 256 * i;
        int r = ch >> 3;
        int c = ch & 7;
        uint4 v = *(const uint4*)(Bsrc + (size_t)(bcol + r) * DIM + k0 + c * 8);
        int off = r * (BK * 2) + ((c * 16) ^ ((r & 7) << 4));
        *(uint4*)(sB + off) = v;
      }
      __syncthreads();
      bf16x8 aF[4][2], bF[4][2];
#pragma unroll
      for (int m = 0; m < 4; ++m)
#pragma unroll
        for (int kk = 0; kk < 2; ++kk) {
          aF[m][kk] = *(const bf16x8*)(sA + aOff[m][kk]);
          bF[m][kk] = *(const bf16x8*)(sB + bOff[m][kk]);
        }
#pragma unroll
      for (int kk = 0; kk < 2; ++kk)
#pragma unroll
        for (int m = 0; m < 4; ++m)
#pragma unroll
          for (int n = 0; n < 4; ++n)
            acc[m][n] = __builtin_amdgcn_mfma_f32_16x16x32_bf16(
                aF[m][kk], bF[n][kk], acc[m][n], 0, 0, 0);
    }
  }

#pragma unroll
  for (int m = 0; m < 4; ++m) {
    int rbase = brow + wrow + m * 16 + (lane >> 4) * 4;
#pragma unroll
    for (int j = 0; j < 4; ++j) {
      int row = rbase + j;
      bool pass = (flags[row] == 2);
#pragma unroll
      for (int n = 0; n < 4; ++n) {
        int col = bcol + wcol + n * 16 + (lane & 15);
        float v = acc[m][n][j];
        if (pass) v += h[(size_t)row * DIM + col];
        out[(size_t)row * DIM + col] = v;
      }
    }
  }
}

extern "C" void kernel_launch(void* const* d_in, const int* in_sizes, int n_in,
                              void* d_out, int out_size, void* d_ws, size_t ws_size,
                              hipStream_t stream) {
  const float* x = (const float*)d_in[0];
  const float* h = (const float*)d_in[1];
  const float* W_ih = (const float*)d_in[2];
  const float* W_hh = (const float*)d_in[3];
  const float* W_inv = (const float*)d_in[4];
  float* out = (float*)d_out;

  char* ws = (char*)d_ws;
  int* flags = (int*)ws;                                   // 64 KB
  int* counts = (int*)(ws + (64 << 10));                   // 256 B
  int* rowmapF = (int*)(ws + (64 << 10) + 256);            // 64 KB
  int* rowmapI = rowmapF + B_ROWS;                         // 64 KB
  u16* WihB = (u16*)(ws + (192 << 10) + 256);              // 8 MB
  u16* WhhT = WihB + (size_t)DIM * DIM;                    // 8 MB
  u16* WinvT = WhhT + (size_t)DIM * DIM;                   // 8 MB
  u16* xb = WinvT + (size_t)DIM * DIM;                     // 64 MB
  u16* hCF = xb + (size_t)B_ROWS * DIM;                    // 64 MB
  u16* hCI = hCF + (size_t)B_ROWS * DIM;                   // 64 MB
  size_t need = (size_t)(192 << 10) + 256 + 3ull * DIM * DIM * 2 +
                3ull * B_ROWS * DIM * 2;

  k_convert<<<(DIM * DIM / 4) / 256, 256, 0, stream>>>(W_ih, WihB);
  k_transpose<<<dim3(DIM / 32, DIM / 32), 256, 0, stream>>>(W_hh, WhhT);
  k_transpose<<<dim3(DIM / 32, DIM / 32), 256, 0, stream>>>(W_inv, WinvT);

  if (ws_size >= need) {
    hipMemsetAsync(counts, 0, 2 * sizeof(int), stream);
    k_prep<<<B_ROWS / 4, 256, 0, stream>>>(x, h, W_ih, flags, xb, hCF, hCI,
                                           rowmapF, rowmapI, counts);
    k_gemm1<<<(B_ROWS / BM) * (DIM / BN), 256, 0, stream>>>(xb, WihB, flags, h,
                                                            out);
    k_gemm2<<<2 * (B_ROWS / BM) * (DIM / BN), 256, 0, stream>>>(
        hCF, hCI, WhhT, WinvT, rowmapF, rowmapI, counts, out);
  } else {
    k_flags_fb<<<B_ROWS / 4, 256, 0, stream>>>(x, h, W_ih, flags);
    k_gemm_fb<<<(B_ROWS / BM) * (DIM / BN), 256, 0, stream>>>(x, h, WihB, WhhT,
                                                              WinvT, flags, out);
  }
}